// Round 8
// baseline (608.945 us; speedup 1.0000x reference)
//
#include <hip/hip_runtime.h>

typedef _Float16 f16;
typedef _Float16 f16x8 __attribute__((ext_vector_type(8)));
typedef float f32x4 __attribute__((ext_vector_type(4)));

#define MFMA16(a,b,c) __builtin_amdgcn_mfma_f32_16x16x32_f16((a),(b),(c),0,0,0)

// slab layout: tab[chunk][node][16] halfs, chunk = col/16 (8 chunks, 3.2 MB each)

// ---------------- index dtype detection (parallel) ----------------
__global__ void k_detect(const long long* ei, int n_nodes, int* flag) {
    long long v = ei[threadIdx.x];
    int bad = (v < 0 || v >= n_nodes);
    unsigned long long m = __ballot(bad);
    if (threadIdx.x == 0) *flag = (m == 0ULL);   // 1 => int64, 0 => int32
}

__global__ void k_idx(const void* ei, int E, const int* __restrict__ flag,
                      int* __restrict__ src, int* __restrict__ dst) {
    int e = blockIdx.x * 256 + threadIdx.x;
    if (e >= E) return;
    if (*flag) {
        const long long* p = (const long long*)ei;
        src[e] = (int)p[e];
        dst[e] = (int)p[(size_t)E + e];
    } else {
        const int* p = (const int*)ei;
        src[e] = p[e];
        dst[e] = p[(size_t)E + e];
    }
}

// ---------------- fp32 -> fp16 convert, row-major x -> slab xh ----------------
__global__ void k_x2h(const float* __restrict__ x, f16* __restrict__ xs, int N) {
    int i = blockIdx.x * 256 + threadIdx.x;      // one 8-half group per thread
    if (i >= N * 16) return;
    int n = i >> 4, cg = i & 15;
    const float* px = x + (size_t)n * 128 + cg * 8;
    float4 a = *(const float4*)px;
    float4 b = *(const float4*)(px + 4);
    f16x8 h;
    h[0] = (f16)a.x; h[1] = (f16)a.y; h[2] = (f16)a.z; h[3] = (f16)a.w;
    h[4] = (f16)b.x; h[5] = (f16)b.y; h[6] = (f16)b.z; h[7] = (f16)b.w;
    int chunk = cg >> 1, off = (cg & 1) * 8;
    *(f16x8*)(xs + ((size_t)chunk * N + n) * 16 + off) = h;
}

// ---------------- SAGE W -> fp16 frag-ordered ----------------
__global__ void k_wfrag(const float* __restrict__ Wa, const float* __restrict__ Wb,
                        f16* __restrict__ dst, int KS) {
    int t = blockIdx.x * 256 + threadIdx.x;
    int total = KS * 8 * 64;
    if (t >= total) return;
    int l = t & 63;
    int s = t >> 9;
    int k0 = s * 32 + (l >> 4) * 8;
    int j = ((t >> 6) & 7) * 16 + (l & 15);
    f16x8 h;
    #pragma unroll
    for (int e = 0; e < 8; e++) {
        int k = k0 + e;
        float v = (k < 128) ? Wa[k * 128 + j] : Wb[(k - 128) * 128 + j];
        h[e] = (f16)v;
    }
    *(f16x8*)(dst + (size_t)t * 8) = h;
}

// ---------------- z-GEMM W frags ----------------
__global__ void k_zfrag(const float* __restrict__ Wm1, f16* __restrict__ dst) {
    int t = blockIdx.x * 256 + threadIdx.x;
    if (t >= 4 * 16 * 64) return;
    int lane = t & 63, c = (t >> 6) & 15, s = t >> 10;
    int k0 = s * 32 + (lane >> 4) * 8;
    int j = c * 16 + (lane & 15);
    f16x8 h;
    #pragma unroll
    for (int e = 0; e < 8; e++) {
        int k = k0 + e;
        float v = (j < 128) ? Wm1[k * 128 + j] : Wm1[(128 + k) * 128 + (j - 128)];
        h[e] = (f16)v;
    }
    *(f16x8*)(dst + (size_t)t * 8) = h;
}

// ---------------- edge-attr W frags (W1e = Wm1 rows 256..271), K padded to 32 ----------------
__global__ void k_wefrag(const float* __restrict__ Wm1, f16* __restrict__ dst) {
    int t = blockIdx.x * 256 + threadIdx.x;
    if (t >= 8 * 64) return;
    int lane = t & 63, ct = t >> 6;
    int k0 = (lane >> 4) * 8;
    int j = ct * 16 + (lane & 15);
    f16x8 h;
    #pragma unroll
    for (int e = 0; e < 8; e++) {
        int k = k0 + e;
        h[e] = (k < 16) ? (f16)Wm1[(256 + k) * 128 + j] : (f16)0.0f;
    }
    *(f16x8*)(dst + (size_t)t * 8) = h;
}

// ---------------- CSR build ----------------
__global__ void k_hist(const int* __restrict__ dst, int E, int* __restrict__ deg) {
    int e = blockIdx.x * 256 + threadIdx.x;
    if (e < E) atomicAdd(&deg[dst[e]], 1);
}

__global__ void k_bsum(const int* __restrict__ deg, int n, int* __restrict__ bsum) {
    __shared__ int ws[4];
    const int tid = threadIdx.x;
    int i = blockIdx.x * 1024 + tid * 4;
    int s = 0;
    if (i + 3 < n) {
        int4 d = *(const int4*)(deg + i);
        s = d.x + d.y + d.z + d.w;
    } else {
        #pragma unroll
        for (int j = 0; j < 4; j++) if (i + j < n) s += deg[i + j];
    }
    #pragma unroll
    for (int m = 1; m < 64; m <<= 1) s += __shfl_xor(s, m, 64);
    if ((tid & 63) == 0) ws[tid >> 6] = s;
    __syncthreads();
    if (tid == 0) bsum[blockIdx.x] = ws[0] + ws[1] + ws[2] + ws[3];
}

__global__ void k_bscan(int* __restrict__ bsum, int nb, int* __restrict__ rowptr_n) {
    __shared__ int wsum[4];
    const int tid = threadIdx.x, lane = tid & 63, wid = tid >> 6;
    int v = (tid < nb) ? bsum[tid] : 0;
    int inc = v;
    #pragma unroll
    for (int off = 1; off < 64; off <<= 1) {
        int u = __shfl_up(inc, off, 64);
        if (lane >= off) inc += u;
    }
    if (lane == 63) wsum[wid] = inc;
    __syncthreads();
    int woff = 0;
    for (int j = 0; j < wid; j++) woff += wsum[j];
    int excl = woff + inc - v;
    if (tid < nb) bsum[tid] = excl;
    if (tid == nb - 1) rowptr_n[0] = excl + v;
}

__global__ void k_rowptr(const int* __restrict__ deg, int n, const int* __restrict__ boff,
                         int* __restrict__ rowptr, int* __restrict__ cursor) {
    __shared__ int wsum[4];
    const int tid = threadIdx.x, lane = tid & 63, wid = tid >> 6;
    int i = blockIdx.x * 1024 + tid * 4;
    int d0 = 0, d1 = 0, d2 = 0, d3 = 0;
    if (i + 3 < n) {
        int4 d = *(const int4*)(deg + i);
        d0 = d.x; d1 = d.y; d2 = d.z; d3 = d.w;
    } else {
        if (i     < n) d0 = deg[i];
        if (i + 1 < n) d1 = deg[i + 1];
        if (i + 2 < n) d2 = deg[i + 2];
        if (i + 3 < n) d3 = deg[i + 3];
    }
    int s = d0 + d1 + d2 + d3;
    int inc = s;
    #pragma unroll
    for (int off = 1; off < 64; off <<= 1) {
        int u = __shfl_up(inc, off, 64);
        if (lane >= off) inc += u;
    }
    if (lane == 63) wsum[wid] = inc;
    __syncthreads();
    int woff = 0;
    for (int j = 0; j < wid; j++) woff += wsum[j];
    int excl = boff[blockIdx.x] + woff + inc - s;
    int e1 = excl + d0, e2 = e1 + d1, e3 = e2 + d2;
    if (i     < n) { rowptr[i]     = excl; cursor[i]     = excl; }
    if (i + 1 < n) { rowptr[i + 1] = e1;   cursor[i + 1] = e1; }
    if (i + 2 < n) { rowptr[i + 2] = e2;   cursor[i + 2] = e2; }
    if (i + 3 < n) { rowptr[i + 3] = e3;   cursor[i + 3] = e3; }
}

__global__ void k_scatter(const int* __restrict__ src, const int* __restrict__ dst, int E,
                          int* __restrict__ cursor, int* __restrict__ col) {
    int e = blockIdx.x * 256 + threadIdx.x;
    if (e < E) {
        int p = atomicAdd(&cursor[dst[e]], 1);
        col[p] = src[e];
    }
}

// ---------------- slab aggregation: chunk = blockIdx % 8 -> XCD-pinned L2-resident slab ----------------
// 2-lane team per node, 128 nodes/block; gathers 16B from a 3.2 MB slab
__global__ __launch_bounds__(256) void k_aggs(
    const f16* __restrict__ tabs, const int* __restrict__ rowptr,
    const int* __restrict__ col, f16* __restrict__ means, int N) {
    const int chunk = blockIdx.x & 7;
    const int tile = blockIdx.x >> 3;
    const int team = threadIdx.x >> 1, half = threadIdx.x & 1;
    const int node = tile * 128 + team;
    if (node >= N) return;
    const f16* slab = tabs + (size_t)chunk * N * 16 + half * 8;
    const int s0 = rowptr[node], s1 = rowptr[node + 1];
    float acc[8] = {0.f, 0.f, 0.f, 0.f, 0.f, 0.f, 0.f, 0.f};
    int k = s0;
    for (; k + 3 < s1; k += 4) {
        const int n0 = col[k], n1 = col[k + 1], n2 = col[k + 2], n3 = col[k + 3];
        f16x8 v0 = *(const f16x8*)(slab + (size_t)n0 * 16);
        f16x8 v1 = *(const f16x8*)(slab + (size_t)n1 * 16);
        f16x8 v2 = *(const f16x8*)(slab + (size_t)n2 * 16);
        f16x8 v3 = *(const f16x8*)(slab + (size_t)n3 * 16);
        #pragma unroll
        for (int j = 0; j < 8; j++)
            acc[j] += ((float)v0[j] + (float)v1[j]) + ((float)v2[j] + (float)v3[j]);
    }
    for (; k < s1; ++k) {
        const int n0 = col[k];
        f16x8 v0 = *(const f16x8*)(slab + (size_t)n0 * 16);
        #pragma unroll
        for (int j = 0; j < 8; j++) acc[j] += (float)v0[j];
    }
    int d = s1 - s0; if (d < 1) d = 1;
    const float inv = 1.f / (float)d;
    f16x8 r;
    #pragma unroll
    for (int j = 0; j < 8; j++) r[j] = (f16)(acc[j] * inv);
    *(f16x8*)(means + ((size_t)chunk * N + node) * 16 + half * 8) = r;
}

// ---------------- layer-1 GEMM from slabs: h = relu([mean|self] @ W + b) -> h1 slab ----------------
__global__ __launch_bounds__(256) void k_gemm2(
    const f16* __restrict__ As, const f16* __restrict__ Ss,
    const f16* __restrict__ Wf, const float* __restrict__ bias,
    f16* __restrict__ outs, int N) {
    const int tid = threadIdx.x, lane = tid & 63, w = tid >> 6;
    const int l15 = lane & 15, g = lane >> 4;
    const int base = blockIdx.x * 64;
    const int c0 = (2 * w) * 16 + l15, c1 = c0 + 16;
    const float b0 = bias[c0], b1 = bias[c1];
    const int chp = g >> 1, off = (g & 1) * 8;
    f32x4 acc[4][2];
    #pragma unroll
    for (int t = 0; t < 4; t++) {
        acc[t][0] = f32x4{b0, b0, b0, b0};
        acc[t][1] = f32x4{b1, b1, b1, b1};
    }
    #pragma unroll
    for (int s = 0; s < 8; s++) {
        f16x8 bf0 = *(const f16x8*)&Wf[((size_t)(s * 8 + 2 * w    ) * 64 + lane) * 8];
        f16x8 bf1 = *(const f16x8*)&Wf[((size_t)(s * 8 + 2 * w + 1) * 64 + lane) * 8];
        const f16* Asrc = (s < 4) ? As : Ss;
        const int chunk = (s & 3) * 2 + chp;
        #pragma unroll
        for (int t = 0; t < 4; t++) {
            int row = base + t * 16 + l15;
            if (row >= N) row = N - 1;
            f16x8 a = *(const f16x8*)(Asrc + ((size_t)chunk * N + row) * 16 + off);
            acc[t][0] = MFMA16(a, bf0, acc[t][0]);
            acc[t][1] = MFMA16(a, bf1, acc[t][1]);
        }
    }
    #pragma unroll
    for (int t = 0; t < 4; t++) {
        #pragma unroll
        for (int i = 0; i < 4; i++) {
            int row = base + t * 16 + g * 4 + i;
            if (row < N) {
                float v0 = acc[t][0][i]; v0 = v0 > 0.f ? v0 : 0.f;
                float v1 = acc[t][1][i]; v1 = v1 > 0.f ? v1 : 0.f;
                outs[((size_t)(2 * w    ) * N + row) * 16 + l15] = (f16)v0;
                outs[((size_t)(2 * w + 1) * N + row) * 16 + l15] = (f16)v1;
            }
        }
    }
}

// ---------------- layer-2 GEMM + z-GEMM fused: z = [h2@W1s | h2@W1d + bm1] (row-major) ----------------
#define AP 136
__global__ __launch_bounds__(256, 3) void k_gemmz(
    const f16* __restrict__ As, const f16* __restrict__ Ss,
    const f16* __restrict__ Wf, const float* __restrict__ bias,
    const f16* __restrict__ zwf, const float* __restrict__ bm1,
    f16* __restrict__ z, int N) {
    __shared__ __align__(16) f16 sA[64 * AP];
    const int tid = threadIdx.x, lane = tid & 63, w = tid >> 6;
    const int l15 = lane & 15, g = lane >> 4;
    const int base = blockIdx.x * 64;
    const int c0 = (2 * w) * 16 + l15, c1 = c0 + 16;
    const float b0 = bias[c0], b1 = bias[c1];
    const int chp = g >> 1, off = (g & 1) * 8;
    f32x4 acc[4][2];
    #pragma unroll
    for (int t = 0; t < 4; t++) {
        acc[t][0] = f32x4{b0, b0, b0, b0};
        acc[t][1] = f32x4{b1, b1, b1, b1};
    }
    #pragma unroll
    for (int s = 0; s < 8; s++) {
        f16x8 bf0 = *(const f16x8*)&Wf[((size_t)(s * 8 + 2 * w    ) * 64 + lane) * 8];
        f16x8 bf1 = *(const f16x8*)&Wf[((size_t)(s * 8 + 2 * w + 1) * 64 + lane) * 8];
        const f16* Asrc = (s < 4) ? As : Ss;
        const int chunk = (s & 3) * 2 + chp;
        #pragma unroll
        for (int t = 0; t < 4; t++) {
            int row = base + t * 16 + l15;
            if (row >= N) row = N - 1;
            f16x8 a = *(const f16x8*)(Asrc + ((size_t)chunk * N + row) * 16 + off);
            acc[t][0] = MFMA16(a, bf0, acc[t][0]);
            acc[t][1] = MFMA16(a, bf1, acc[t][1]);
        }
    }
    // h2 tile (fp16-rounded, relu) -> sA
    #pragma unroll
    for (int t = 0; t < 4; t++) {
        #pragma unroll
        for (int i = 0; i < 4; i++) {
            const int rl = t * 16 + g * 4 + i;
            float v0 = acc[t][0][i]; v0 = v0 > 0.f ? v0 : 0.f;
            float v1 = acc[t][1][i]; v1 = v1 > 0.f ? v1 : 0.f;
            sA[rl * AP + c0] = (f16)v0;
            sA[rl * AP + c1] = (f16)v1;
        }
    }
    __syncthreads();
    // z-GEMM (256 cols, two halves to cap VGPR)
    #pragma unroll
    for (int half = 0; half < 2; half++) {
        const int j0 = (4 * w + 2 * half) * 16 + l15, j1 = j0 + 16;
        const float zb0 = (j0 >= 128) ? bm1[j0 - 128] : 0.0f;
        const float zb1 = (j1 >= 128) ? bm1[j1 - 128] : 0.0f;
        f32x4 zacc[4][2];
        #pragma unroll
        for (int t = 0; t < 4; t++) {
            zacc[t][0] = f32x4{zb0, zb0, zb0, zb0};
            zacc[t][1] = f32x4{zb1, zb1, zb1, zb1};
        }
        #pragma unroll
        for (int s = 0; s < 4; s++) {
            f16x8 wf0 = *(const f16x8*)&zwf[((size_t)(s * 16 + 4 * w + 2 * half    ) * 64 + lane) * 8];
            f16x8 wf1 = *(const f16x8*)&zwf[((size_t)(s * 16 + 4 * w + 2 * half + 1) * 64 + lane) * 8];
            const int koff = s * 32 + g * 8;
            #pragma unroll
            for (int t = 0; t < 4; t++) {
                f16x8 a = *(const f16x8*)&sA[(t * 16 + l15) * AP + koff];
                zacc[t][0] = MFMA16(a, wf0, zacc[t][0]);
                zacc[t][1] = MFMA16(a, wf1, zacc[t][1]);
            }
        }
        #pragma unroll
        for (int t = 0; t < 4; t++) {
            #pragma unroll
            for (int i = 0; i < 4; i++) {
                int row = base + t * 16 + g * 4 + i;
                if (row < N) {
                    z[(size_t)row * 256 + j0] = (f16)zacc[t][0][i];
                    z[(size_t)row * 256 + j1] = (f16)zacc[t][1][i];
                }
            }
        }
    }
}

// ---------------- edge kernel (unchanged from R6: fill-path-bound, ~150 µs) ----------------
#define ZP 136
__global__ __launch_bounds__(256, 4) void k_edge2(
    const f16* __restrict__ z, const float* __restrict__ ea,
    const int* __restrict__ src, const int* __restrict__ dst,
    const f16* __restrict__ wef, const float* __restrict__ Wm2,
    const float* __restrict__ bm2, float* __restrict__ out,
    int E, int iters, int gridW) {
    __shared__ __align__(16) f16 sZ[64 * ZP];
    __shared__ __align__(16) f16 sEA[4 * 64 * 8];
    __shared__ float sPart[4][64];
    const int tid = threadIdx.x, lane = tid & 63, w = tid >> 6;
    const int l15 = lane & 15, g = lane >> 4;
    const int sr = lane >> 2, sq = lane & 3;
    const int slot_s = w * 16 + sr;

    for (int i = tid; i < 4 * 64; i += 256)
        *(f16x8*)(&sEA[0] + (size_t)i * 8) = f16x8{};

    const f16x8 be0 = *(const f16x8*)(wef + ((size_t)((2 * w) * 64 + lane)) * 8);
    const f16x8 be1 = *(const f16x8*)(wef + ((size_t)((2 * w + 1) * 64 + lane)) * 8);
    const float w20 = Wm2[(2 * w) * 16 + l15];
    const float w21 = Wm2[(2 * w + 1) * 16 + l15];
    const float bv = bm2[0];

    f16x8 zs[4], zd[4];
    union { f16 h[4]; uint2 u2; } eh;

    auto stage_load = [&](int ebase) {
        int er = ebase + slot_s; if (er > E - 1) er = E - 1;
        const int is = src[er], id = dst[er];
        const f16* ps = z + (size_t)is * 256 + sq * 32;
        const f16* pd = z + (size_t)id * 256 + 128 + sq * 32;
        #pragma unroll
        for (int i = 0; i < 4; i++) {
            zs[i] = *(const f16x8*)(ps + i * 8);
            zd[i] = *(const f16x8*)(pd + i * 8);
        }
        float4 ev = *(const float4*)(ea + (size_t)er * 16 + sq * 4);
        eh.h[0] = (f16)ev.x; eh.h[1] = (f16)ev.y; eh.h[2] = (f16)ev.z; eh.h[3] = (f16)ev.w;
    };
    auto stage_write = [&]() {
        f16* zp = &sZ[0] + slot_s * ZP + sq * 32;
        #pragma unroll
        for (int i = 0; i < 4; i++) {
            f16x8 v = zs[i] + zd[i];
            *(f16x8*)(zp + i * 8) = v;
        }
        f16* ep = &sEA[0] +
                  ((size_t)((slot_s >> 4) * 64 + (sq >> 1) * 16 + (slot_s & 15)) * 8 + (sq & 1) * 4);
        *(uint2*)ep = eh.u2;
    };

    stage_load(blockIdx.x * 64);
    __syncthreads();
    stage_write();
    __syncthreads();

    for (int it = 0; it < iters; ++it) {
        const int ebase = (blockIdx.x + it * gridW) * 64;
        if (ebase >= E) break;
        const int nxt = (blockIdx.x + (it + 1) * gridW) * 64;
        const bool has_next = (it + 1 < iters) && (nxt < E);
        if (has_next) stage_load(nxt);

        f32x4 acc[4][2];
        #pragma unroll
        for (int t = 0; t < 4; t++) { acc[t][0] = f32x4{0,0,0,0}; acc[t][1] = f32x4{0,0,0,0}; }
        #pragma unroll
        for (int t = 0; t < 4; t++) {
            f16x8 a = *(const f16x8*)(&sEA[0] + ((size_t)(t * 64 + lane)) * 8);
            acc[t][0] = MFMA16(a, be0, acc[t][0]);
            acc[t][1] = MFMA16(a, be1, acc[t][1]);
        }
        #pragma unroll
        for (int t = 0; t < 4; t++) {
            float p[4];
            #pragma unroll
            for (int i = 0; i < 4; i++) {
                int slot = t * 16 + g * 4 + i;
                float z0 = (float)sZ[slot * ZP + (2 * w) * 16 + l15];
                float z1 = (float)sZ[slot * ZP + (2 * w + 1) * 16 + l15];
                float v0 = z0 + acc[t][0][i]; v0 = v0 > 0.f ? v0 : 0.f;
                float v1 = z1 + acc[t][1][i]; v1 = v1 > 0.f ? v1 : 0.f;
                p[i] = v0 * w20 + v1 * w21;
            }
            #pragma unroll
            for (int m = 1; m < 16; m <<= 1)
                #pragma unroll
                for (int i = 0; i < 4; i++) p[i] += __shfl_xor(p[i], m, 64);
            if (l15 == 0)
                #pragma unroll
                for (int i = 0; i < 4; i++) sPart[w][t * 16 + g * 4 + i] = p[i];
        }
        __syncthreads();
        if (tid < 64) {
            int e = ebase + tid;
            if (e < E)
                out[e] = sPart[0][tid] + sPart[1][tid] + sPart[2][tid] + sPart[3][tid] + bv;
        }
        if (has_next) stage_write();
        __syncthreads();
    }
}

// ---------------- host launch ----------------
extern "C" void kernel_launch(void* const* d_in, const int* in_sizes, int n_in,
                              void* d_out, int out_size, void* d_ws, size_t ws_size,
                              hipStream_t stream) {
    const float* x   = (const float*)d_in[0];
    const void*  ei  = d_in[1];
    const float* ea  = (const float*)d_in[2];
    const float* Wl1 = (const float*)d_in[3];
    const float* Wr1 = (const float*)d_in[4];
    const float* b1  = (const float*)d_in[5];
    const float* Wl2 = (const float*)d_in[6];
    const float* Wr2 = (const float*)d_in[7];
    const float* b2  = (const float*)d_in[8];
    const float* Wm1 = (const float*)d_in[9];
    const float* bm1 = (const float*)d_in[10];
    const float* Wm2 = (const float*)d_in[11];
    const float* bm2 = (const float*)d_in[12];

    const int N = in_sizes[0] / 128;
    const int E = in_sizes[1] / 2;

    char* ws = (char*)d_ws;
    size_t off = 0;
    auto alloc = [&](size_t bytes) -> void* {
        void* p = ws + off;
        off = (off + bytes + 255) & ~(size_t)255;
        return p;
    };
    // z [N][256] row-major; xh slab aliases its first half (xh dead before z written)
    f16* z      = (f16*)alloc((size_t)N * 256 * 2);
    f16* xh     = z;                                   // slab format [8][N][16]
    f16* h1     = (f16*)alloc((size_t)N * 128 * 2);    // slab format
    f16* mean   = (f16*)alloc((size_t)N * 128 * 2);    // slab format
    int* src    = (int*)alloc((size_t)E * 4);
    int* dst    = (int*)alloc((size_t)E * 4);
    int* col    = (int*)alloc((size_t)E * 4);
    int* deg    = (int*)alloc((size_t)N * 4);
    int* rowptr = (int*)alloc((size_t)(N + 1) * 4);
    int* cursor = (int*)alloc((size_t)N * 4);
    int* bsum   = (int*)alloc((size_t)1024 * 4);
    f16* w1f    = (f16*)alloc((size_t)8 * 8 * 64 * 8 * 2);
    f16* w2f    = (f16*)alloc((size_t)8 * 8 * 64 * 8 * 2);
    f16* zwf    = (f16*)alloc((size_t)4 * 16 * 64 * 8 * 2);
    f16* wef    = (f16*)alloc((size_t)8 * 64 * 8 * 2);
    int* flag   = (int*)alloc(4);
    if (off > ws_size) return;

    const int eb = (E + 255) / 256;
    const int nbk = (N + 1023) / 1024;
    const int rb64 = (N + 63) / 64;

    k_detect<<<1, 64, 0, stream>>>((const long long*)ei, N, flag);
    k_idx<<<eb, 256, 0, stream>>>(ei, E, flag, src, dst);
    k_x2h<<<(N * 16 + 255) / 256, 256, 0, stream>>>(x, xh, N);
    k_wfrag<<<16, 256, 0, stream>>>(Wl1, Wr1, w1f, 8);
    k_wfrag<<<16, 256, 0, stream>>>(Wl2, Wr2, w2f, 8);
    k_zfrag<<<16, 256, 0, stream>>>(Wm1, zwf);
    k_wefrag<<<2, 256, 0, stream>>>(Wm1, wef);

    hipMemsetAsync(deg, 0, (size_t)N * 4, stream);
    k_hist<<<eb, 256, 0, stream>>>(dst, E, deg);
    k_bsum<<<nbk, 256, 0, stream>>>(deg, N, bsum);
    k_bscan<<<1, 256, 0, stream>>>(bsum, nbk, rowptr + N);
    k_rowptr<<<nbk, 256, 0, stream>>>(deg, N, bsum, rowptr, cursor);
    k_scatter<<<eb, 256, 0, stream>>>(src, dst, E, cursor, col);

    const int ag = 8 * ((N + 127) / 128);   // chunk = blockIdx % 8 -> XCD-pinned

    // layer 1
    k_aggs<<<ag, 256, 0, stream>>>(xh, rowptr, col, mean, N);
    k_gemm2<<<rb64, 256, 0, stream>>>(mean, xh, w1f, b1, h1, N);
    // layer 2 (+ fused z-GEMM; h2 never materialized)
    k_aggs<<<ag, 256, 0, stream>>>(h1, rowptr, col, mean, N);
    k_gemmz<<<rb64, 256, 0, stream>>>(mean, h1, w2f, b2, zwf, bm1, z, N);

    const int eg = 1792;
    const int nb = (E + 63) / 64;
    const int e_iters = (nb + eg - 1) / eg;
    k_edge2<<<eg, 256, 0, stream>>>(z, ea, src, dst, wef, Wm2, bm2,
                                    (float*)d_out, E, e_iters, eg);
}

// Round 9
// 559.075 us; speedup vs baseline: 1.0892x; 1.0892x over previous
//
#include <hip/hip_runtime.h>

typedef _Float16 f16;
typedef _Float16 f16x8 __attribute__((ext_vector_type(8)));
typedef float f32x4 __attribute__((ext_vector_type(4)));

#define MFMA16(a,b,c) __builtin_amdgcn_mfma_f32_16x16x32_f16((a),(b),(c),0,0,0)

// ---------------- index dtype detection (parallel) ----------------
__global__ void k_detect(const long long* ei, int n_nodes, int* flag) {
    long long v = ei[threadIdx.x];
    int bad = (v < 0 || v >= n_nodes);
    unsigned long long m = __ballot(bad);
    if (threadIdx.x == 0) *flag = (m == 0ULL);   // 1 => int64, 0 => int32
}

// fused: index extraction + degree histogram (deg pre-zeroed)
__global__ void k_idx(const void* ei, int E, const int* __restrict__ flag,
                      int* __restrict__ src, int* __restrict__ dst,
                      int* __restrict__ deg) {
    int e = blockIdx.x * 256 + threadIdx.x;
    if (e >= E) return;
    int s, d;
    if (*flag) {
        const long long* p = (const long long*)ei;
        s = (int)p[e];
        d = (int)p[(size_t)E + e];
    } else {
        const int* p = (const int*)ei;
        s = p[e];
        d = p[(size_t)E + e];
    }
    src[e] = s;
    dst[e] = d;
    atomicAdd(&deg[d], 1);
}

// ---------------- fp32 -> fp16 convert (x table, row-major) ----------------
__global__ void k_x2h(const float* __restrict__ x, f16* __restrict__ xh, int n) {
    int i = (blockIdx.x * 256 + threadIdx.x) * 8;
    if (i >= n) return;
    float4 a = *(const float4*)(x + i);
    float4 b = *(const float4*)(x + i + 4);
    f16x8 h;
    h[0] = (f16)a.x; h[1] = (f16)a.y; h[2] = (f16)a.z; h[3] = (f16)a.w;
    h[4] = (f16)b.x; h[5] = (f16)b.y; h[6] = (f16)b.z; h[7] = (f16)b.w;
    *(f16x8*)(xh + i) = h;
}

// ---------------- SAGE W -> fp16 frag-ordered ----------------
__global__ void k_wfrag(const float* __restrict__ Wa, const float* __restrict__ Wb,
                        f16* __restrict__ dst, int KS) {
    int t = blockIdx.x * 256 + threadIdx.x;
    int total = KS * 8 * 64;
    if (t >= total) return;
    int l = t & 63;
    int s = t >> 9;
    int k0 = s * 32 + (l >> 4) * 8;
    int j = ((t >> 6) & 7) * 16 + (l & 15);
    f16x8 h;
    #pragma unroll
    for (int e = 0; e < 8; e++) {
        int k = k0 + e;
        float v = (k < 128) ? Wa[k * 128 + j] : Wb[(k - 128) * 128 + j];
        h[e] = (f16)v;
    }
    *(f16x8*)(dst + (size_t)t * 8) = h;
}

// ---------------- z-GEMM W frags ----------------
__global__ void k_zfrag(const float* __restrict__ Wm1, f16* __restrict__ dst) {
    int t = blockIdx.x * 256 + threadIdx.x;
    if (t >= 4 * 16 * 64) return;
    int lane = t & 63, c = (t >> 6) & 15, s = t >> 10;
    int k0 = s * 32 + (lane >> 4) * 8;
    int j = c * 16 + (lane & 15);
    f16x8 h;
    #pragma unroll
    for (int e = 0; e < 8; e++) {
        int k = k0 + e;
        float v = (j < 128) ? Wm1[k * 128 + j] : Wm1[(128 + k) * 128 + (j - 128)];
        h[e] = (f16)v;
    }
    *(f16x8*)(dst + (size_t)t * 8) = h;
}

// ---------------- edge-attr W frags (W1e = Wm1 rows 256..271), K padded to 32 ----------------
__global__ void k_wefrag(const float* __restrict__ Wm1, f16* __restrict__ dst) {
    int t = blockIdx.x * 256 + threadIdx.x;
    if (t >= 8 * 64) return;
    int lane = t & 63, ct = t >> 6;
    int k0 = (lane >> 4) * 8;
    int j = ct * 16 + (lane & 15);
    f16x8 h;
    #pragma unroll
    for (int e = 0; e < 8; e++) {
        int k = k0 + e;
        h[e] = (k < 16) ? (f16)Wm1[(256 + k) * 128 + j] : (f16)0.0f;
    }
    *(f16x8*)(dst + (size_t)t * 8) = h;
}

// ---------------- CSR build ----------------
__global__ void k_bsum(const int* __restrict__ deg, int n, int* __restrict__ bsum) {
    __shared__ int ws[4];
    const int tid = threadIdx.x;
    int i = blockIdx.x * 1024 + tid * 4;
    int s = 0;
    if (i + 3 < n) {
        int4 d = *(const int4*)(deg + i);
        s = d.x + d.y + d.z + d.w;
    } else {
        #pragma unroll
        for (int j = 0; j < 4; j++) if (i + j < n) s += deg[i + j];
    }
    #pragma unroll
    for (int m = 1; m < 64; m <<= 1) s += __shfl_xor(s, m, 64);
    if ((tid & 63) == 0) ws[tid >> 6] = s;
    __syncthreads();
    if (tid == 0) bsum[blockIdx.x] = ws[0] + ws[1] + ws[2] + ws[3];
}

__global__ void k_bscan(int* __restrict__ bsum, int nb, int* __restrict__ rowptr_n) {
    __shared__ int wsum[4];
    const int tid = threadIdx.x, lane = tid & 63, wid = tid >> 6;
    int v = (tid < nb) ? bsum[tid] : 0;
    int inc = v;
    #pragma unroll
    for (int off = 1; off < 64; off <<= 1) {
        int u = __shfl_up(inc, off, 64);
        if (lane >= off) inc += u;
    }
    if (lane == 63) wsum[wid] = inc;
    __syncthreads();
    int woff = 0;
    for (int j = 0; j < wid; j++) woff += wsum[j];
    int excl = woff + inc - v;
    if (tid < nb) bsum[tid] = excl;
    if (tid == nb - 1) rowptr_n[0] = excl + v;
}

__global__ void k_rowptr(const int* __restrict__ deg, int n, const int* __restrict__ boff,
                         int* __restrict__ rowptr, int* __restrict__ cursor) {
    __shared__ int wsum[4];
    const int tid = threadIdx.x, lane = tid & 63, wid = tid >> 6;
    int i = blockIdx.x * 1024 + tid * 4;
    int d0 = 0, d1 = 0, d2 = 0, d3 = 0;
    if (i + 3 < n) {
        int4 d = *(const int4*)(deg + i);
        d0 = d.x; d1 = d.y; d2 = d.z; d3 = d.w;
    } else {
        if (i     < n) d0 = deg[i];
        if (i + 1 < n) d1 = deg[i + 1];
        if (i + 2 < n) d2 = deg[i + 2];
        if (i + 3 < n) d3 = deg[i + 3];
    }
    int s = d0 + d1 + d2 + d3;
    int inc = s;
    #pragma unroll
    for (int off = 1; off < 64; off <<= 1) {
        int u = __shfl_up(inc, off, 64);
        if (lane >= off) inc += u;
    }
    if (lane == 63) wsum[wid] = inc;
    __syncthreads();
    int woff = 0;
    for (int j = 0; j < wid; j++) woff += wsum[j];
    int excl = boff[blockIdx.x] + woff + inc - s;
    int e1 = excl + d0, e2 = e1 + d1, e3 = e2 + d2;
    if (i     < n) { rowptr[i]     = excl; cursor[i]     = excl; }
    if (i + 1 < n) { rowptr[i + 1] = e1;   cursor[i + 1] = e1; }
    if (i + 2 < n) { rowptr[i + 2] = e2;   cursor[i + 2] = e2; }
    if (i + 3 < n) { rowptr[i + 3] = e3;   cursor[i + 3] = e3; }
}

// scatter: CSR col + original edge id + dst-of-position
__global__ void k_scatter(const int* __restrict__ src, const int* __restrict__ dst, int E,
                          int* __restrict__ cursor, int* __restrict__ col,
                          int* __restrict__ eid, int* __restrict__ dstp) {
    int e = blockIdx.x * 256 + threadIdx.x;
    if (e < E) {
        int d = dst[e];
        int p = atomicAdd(&cursor[d], 1);
        col[p] = src[e];
        eid[p] = e;
        dstp[p] = d;
    }
}

// ---------------- fused layer kernel (R7 structure, proven) ----------------
#define AP 136
template<int DO_Z>
__global__ __launch_bounds__(256, DO_Z ? 3 : 4) void k_fuse(
    const f16* __restrict__ tab,
    const int* __restrict__ rowptr, const int* __restrict__ col,
    const f16* __restrict__ Wf, const float* __restrict__ bias,
    const f16* __restrict__ zwf, const float* __restrict__ bm1,
    f16* __restrict__ out, int n_rows) {
    __shared__ __align__(16) f16 sA[64 * AP];
    const int tid = threadIdx.x, lane = tid & 63, w = tid >> 6;
    const int l15 = lane & 15, g = lane >> 4;
    const int base = blockIdx.x * 64;

    // phase 1: mean aggregation (one 16-lane group per node)
    const int g16 = tid >> 4, c = tid & 15;
    #pragma unroll
    for (int rep = 0; rep < 4; rep++) {
        const int node = base + rep * 16 + g16;
        float acc[8] = {0.f, 0.f, 0.f, 0.f, 0.f, 0.f, 0.f, 0.f};
        int d = 1;
        if (node < n_rows) {
            const int s0 = rowptr[node], s1 = rowptr[node + 1];
            int k = s0;
            for (; k + 3 < s1; k += 4) {
                const int n0 = col[k], n1 = col[k + 1], n2 = col[k + 2], n3 = col[k + 3];
                f16x8 v0 = *(const f16x8*)(tab + (size_t)n0 * 128 + c * 8);
                f16x8 v1 = *(const f16x8*)(tab + (size_t)n1 * 128 + c * 8);
                f16x8 v2 = *(const f16x8*)(tab + (size_t)n2 * 128 + c * 8);
                f16x8 v3 = *(const f16x8*)(tab + (size_t)n3 * 128 + c * 8);
                #pragma unroll
                for (int j = 0; j < 8; j++)
                    acc[j] += ((float)v0[j] + (float)v1[j]) + ((float)v2[j] + (float)v3[j]);
            }
            for (; k < s1; ++k) {
                const int n0 = col[k];
                f16x8 v0 = *(const f16x8*)(tab + (size_t)n0 * 128 + c * 8);
                #pragma unroll
                for (int j = 0; j < 8; j++) acc[j] += (float)v0[j];
            }
            d = s1 - s0; if (d < 1) d = 1;
        }
        const float inv = 1.f / (float)d;
        f16x8 r;
        #pragma unroll
        for (int j = 0; j < 8; j++) r[j] = (f16)(acc[j] * inv);
        *(f16x8*)&sA[(rep * 16 + g16) * AP + c * 8] = r;
    }
    __syncthreads();

    // phase 2: SAGE GEMM tile
    const int c0 = (2 * w) * 16 + l15, c1 = c0 + 16;
    const float b0 = bias[c0], b1 = bias[c1];
    f32x4 acc[4][2];
    #pragma unroll
    for (int t = 0; t < 4; t++) {
        acc[t][0] = f32x4{b0, b0, b0, b0};
        acc[t][1] = f32x4{b1, b1, b1, b1};
    }
    #pragma unroll
    for (int s = 0; s < 8; s++) {
        f16x8 bf0 = *(const f16x8*)&Wf[((size_t)(s * 8 + 2 * w    ) * 64 + lane) * 8];
        f16x8 bf1 = *(const f16x8*)&Wf[((size_t)(s * 8 + 2 * w + 1) * 64 + lane) * 8];
        const int koff = (s & 3) * 32 + g * 8;
        #pragma unroll
        for (int t = 0; t < 4; t++) {
            f16x8 a;
            if (s < 4) {
                a = *(const f16x8*)&sA[(t * 16 + l15) * AP + koff];
            } else {
                int row = base + t * 16 + l15;
                if (row >= n_rows) row = n_rows - 1;
                a = *(const f16x8*)(tab + (size_t)row * 128 + koff);
            }
            acc[t][0] = MFMA16(a, bf0, acc[t][0]);
            acc[t][1] = MFMA16(a, bf1, acc[t][1]);
        }
    }

    if (DO_Z == 0) {
        #pragma unroll
        for (int t = 0; t < 4; t++) {
            #pragma unroll
            for (int i = 0; i < 4; i++) {
                int row = base + t * 16 + g * 4 + i;
                if (row < n_rows) {
                    float v0 = acc[t][0][i]; v0 = v0 > 0.f ? v0 : 0.f;
                    float v1 = acc[t][1][i]; v1 = v1 > 0.f ? v1 : 0.f;
                    out[(size_t)row * 128 + c0] = (f16)v0;
                    out[(size_t)row * 128 + c1] = (f16)v1;
                }
            }
        }
    } else {
        __syncthreads();
        #pragma unroll
        for (int t = 0; t < 4; t++) {
            #pragma unroll
            for (int i = 0; i < 4; i++) {
                const int rl = t * 16 + g * 4 + i;
                float v0 = acc[t][0][i]; v0 = v0 > 0.f ? v0 : 0.f;
                float v1 = acc[t][1][i]; v1 = v1 > 0.f ? v1 : 0.f;
                sA[rl * AP + c0] = (f16)v0;
                sA[rl * AP + c1] = (f16)v1;
            }
        }
        __syncthreads();
        #pragma unroll
        for (int half = 0; half < 2; half++) {
            const int j0 = (4 * w + 2 * half) * 16 + l15, j1 = j0 + 16;
            const float zb0 = (j0 >= 128) ? bm1[j0 - 128] : 0.0f;
            const float zb1 = (j1 >= 128) ? bm1[j1 - 128] : 0.0f;
            f32x4 zacc[4][2];
            #pragma unroll
            for (int t = 0; t < 4; t++) {
                zacc[t][0] = f32x4{zb0, zb0, zb0, zb0};
                zacc[t][1] = f32x4{zb1, zb1, zb1, zb1};
            }
            #pragma unroll
            for (int s = 0; s < 4; s++) {
                f16x8 wf0 = *(const f16x8*)&zwf[((size_t)(s * 16 + 4 * w + 2 * half    ) * 64 + lane) * 8];
                f16x8 wf1 = *(const f16x8*)&zwf[((size_t)(s * 16 + 4 * w + 2 * half + 1) * 64 + lane) * 8];
                const int koff = s * 32 + g * 8;
                #pragma unroll
                for (int t = 0; t < 4; t++) {
                    f16x8 a = *(const f16x8*)&sA[(t * 16 + l15) * AP + koff];
                    zacc[t][0] = MFMA16(a, wf0, zacc[t][0]);
                    zacc[t][1] = MFMA16(a, wf1, zacc[t][1]);
                }
            }
            #pragma unroll
            for (int t = 0; t < 4; t++) {
                #pragma unroll
                for (int i = 0; i < 4; i++) {
                    int row = base + t * 16 + g * 4 + i;
                    if (row < n_rows) {
                        out[(size_t)row * 256 + j0] = (f16)zacc[t][0][i];
                        out[(size_t)row * 256 + j1] = (f16)zacc[t][1][i];
                    }
                }
            }
        }
    }
}

// ---------------- edge kernel v7: CSR-ordered gathers, sequential tmp output ----------------
// position p: is=colp[p] (random), id=dstp[p] (runs of equal values), e=eidp[p] (random, 64B ea rows)
// tmp[p] = Wm2 . relu(z_s[is] + z_d[id] + ea[e] @ W1e) + bm2
#define ZP 136
__global__ __launch_bounds__(256, 4) void k_edge2(
    const f16* __restrict__ z, const float* __restrict__ ea,
    const int* __restrict__ colp, const int* __restrict__ dstp, const int* __restrict__ eidp,
    const f16* __restrict__ wef, const float* __restrict__ Wm2,
    const float* __restrict__ bm2, float* __restrict__ tmp,
    int E, int iters, int gridW) {
    __shared__ __align__(16) f16 sZ[64 * ZP];
    __shared__ __align__(16) f16 sEA[4 * 64 * 8];
    __shared__ float sPart[4][64];
    const int tid = threadIdx.x, lane = tid & 63, w = tid >> 6;
    const int l15 = lane & 15, g = lane >> 4;
    const int sr = lane >> 2, sq = lane & 3;
    const int slot_s = w * 16 + sr;

    for (int i = tid; i < 4 * 64; i += 256)
        *(f16x8*)(&sEA[0] + (size_t)i * 8) = f16x8{};

    const f16x8 be0 = *(const f16x8*)(wef + ((size_t)((2 * w) * 64 + lane)) * 8);
    const f16x8 be1 = *(const f16x8*)(wef + ((size_t)((2 * w + 1) * 64 + lane)) * 8);
    const float w20 = Wm2[(2 * w) * 16 + l15];
    const float w21 = Wm2[(2 * w + 1) * 16 + l15];
    const float bv = bm2[0];

    f16x8 zs[4], zd[4];
    union { f16 h[4]; uint2 u2; } eh;

    auto stage_load = [&](int pbase) {
        int pr = pbase + slot_s; if (pr > E - 1) pr = E - 1;
        const int is = colp[pr], id = dstp[pr], ee = eidp[pr];
        const f16* ps = z + (size_t)is * 256 + sq * 32;
        const f16* pd = z + (size_t)id * 256 + 128 + sq * 32;
        #pragma unroll
        for (int i = 0; i < 4; i++) {
            zs[i] = *(const f16x8*)(ps + i * 8);
            zd[i] = *(const f16x8*)(pd + i * 8);
        }
        float4 ev = *(const float4*)(ea + (size_t)ee * 16 + sq * 4);
        eh.h[0] = (f16)ev.x; eh.h[1] = (f16)ev.y; eh.h[2] = (f16)ev.z; eh.h[3] = (f16)ev.w;
    };
    auto stage_write = [&]() {
        f16* zp = &sZ[0] + slot_s * ZP + sq * 32;
        #pragma unroll
        for (int i = 0; i < 4; i++) {
            f16x8 v = zs[i] + zd[i];
            *(f16x8*)(zp + i * 8) = v;
        }
        f16* ep = &sEA[0] +
                  ((size_t)((slot_s >> 4) * 64 + (sq >> 1) * 16 + (slot_s & 15)) * 8 + (sq & 1) * 4);
        *(uint2*)ep = eh.u2;
    };

    stage_load(blockIdx.x * 64);
    __syncthreads();
    stage_write();
    __syncthreads();

    for (int it = 0; it < iters; ++it) {
        const int pbase = (blockIdx.x + it * gridW) * 64;
        if (pbase >= E) break;
        const int nxt = (blockIdx.x + (it + 1) * gridW) * 64;
        const bool has_next = (it + 1 < iters) && (nxt < E);
        if (has_next) stage_load(nxt);

        f32x4 acc[4][2];
        #pragma unroll
        for (int t = 0; t < 4; t++) { acc[t][0] = f32x4{0,0,0,0}; acc[t][1] = f32x4{0,0,0,0}; }
        #pragma unroll
        for (int t = 0; t < 4; t++) {
            f16x8 a = *(const f16x8*)(&sEA[0] + ((size_t)(t * 64 + lane)) * 8);
            acc[t][0] = MFMA16(a, be0, acc[t][0]);
            acc[t][1] = MFMA16(a, be1, acc[t][1]);
        }
        #pragma unroll
        for (int t = 0; t < 4; t++) {
            float p[4];
            #pragma unroll
            for (int i = 0; i < 4; i++) {
                int slot = t * 16 + g * 4 + i;
                float z0 = (float)sZ[slot * ZP + (2 * w) * 16 + l15];
                float z1 = (float)sZ[slot * ZP + (2 * w + 1) * 16 + l15];
                float v0 = z0 + acc[t][0][i]; v0 = v0 > 0.f ? v0 : 0.f;
                float v1 = z1 + acc[t][1][i]; v1 = v1 > 0.f ? v1 : 0.f;
                p[i] = v0 * w20 + v1 * w21;
            }
            #pragma unroll
            for (int m = 1; m < 16; m <<= 1)
                #pragma unroll
                for (int i = 0; i < 4; i++) p[i] += __shfl_xor(p[i], m, 64);
            if (l15 == 0)
                #pragma unroll
                for (int i = 0; i < 4; i++) sPart[w][t * 16 + g * 4 + i] = p[i];
        }
        __syncthreads();
        if (tid < 64) {
            int p = pbase + tid;
            if (p < E)
                tmp[p] = sPart[0][tid] + sPart[1][tid] + sPart[2][tid] + sPart[3][tid] + bv;
        }
        if (has_next) stage_write();
        __syncthreads();
    }
}

// ---------------- permute: out[eidp[p]] = tmp[p] (random 4B writes into 6.4 MB, L2-absorbed) ----------------
__global__ void k_perm(const float* __restrict__ tmp, const int* __restrict__ eidp,
                       float* __restrict__ out, int E) {
    int p = blockIdx.x * 256 + threadIdx.x;
    if (p < E) out[eidp[p]] = tmp[p];
}

// ---------------- host launch ----------------
extern "C" void kernel_launch(void* const* d_in, const int* in_sizes, int n_in,
                              void* d_out, int out_size, void* d_ws, size_t ws_size,
                              hipStream_t stream) {
    const float* x   = (const float*)d_in[0];
    const void*  ei  = d_in[1];
    const float* ea  = (const float*)d_in[2];
    const float* Wl1 = (const float*)d_in[3];
    const float* Wr1 = (const float*)d_in[4];
    const float* b1  = (const float*)d_in[5];
    const float* Wl2 = (const float*)d_in[6];
    const float* Wr2 = (const float*)d_in[7];
    const float* b2  = (const float*)d_in[8];
    const float* Wm1 = (const float*)d_in[9];
    const float* bm1 = (const float*)d_in[10];
    const float* Wm2 = (const float*)d_in[11];
    const float* bm2 = (const float*)d_in[12];

    const int N = in_sizes[0] / 128;
    const int E = in_sizes[1] / 2;

    char* ws = (char*)d_ws;
    size_t off = 0;
    auto alloc = [&](size_t bytes) -> void* {
        void* p = ws + off;
        off = (off + bytes + 255) & ~(size_t)255;
        return p;
    };
    // z [N][256] row-major; xh aliases its first half (dead before z written)
    f16* z      = (f16*)alloc((size_t)N * 256 * 2);
    f16* xh     = z;
    f16* h1     = (f16*)alloc((size_t)N * 128 * 2);
    int* src    = (int*)alloc((size_t)E * 4);
    int* dst    = (int*)alloc((size_t)E * 4);
    int* col    = (int*)alloc((size_t)E * 4);
    int* eid    = (int*)alloc((size_t)E * 4);
    int* dstp   = (int*)alloc((size_t)E * 4);
    float* tmp  = (float*)alloc((size_t)E * 4);
    int* deg    = (int*)alloc((size_t)N * 4);
    int* rowptr = (int*)alloc((size_t)(N + 1) * 4);
    int* cursor = (int*)alloc((size_t)N * 4);
    int* bsum   = (int*)alloc((size_t)1024 * 4);
    f16* w1f    = (f16*)alloc((size_t)8 * 8 * 64 * 8 * 2);
    f16* w2f    = (f16*)alloc((size_t)8 * 8 * 64 * 8 * 2);
    f16* zwf    = (f16*)alloc((size_t)4 * 16 * 64 * 8 * 2);
    f16* wef    = (f16*)alloc((size_t)8 * 64 * 8 * 2);
    int* flag   = (int*)alloc(4);
    if (off > ws_size) return;

    const int eb = (E + 255) / 256;
    const int nbk = (N + 1023) / 1024;
    const int rb64 = (N + 63) / 64;

    k_detect<<<1, 64, 0, stream>>>((const long long*)ei, N, flag);
    hipMemsetAsync(deg, 0, (size_t)N * 4, stream);
    k_idx<<<eb, 256, 0, stream>>>(ei, E, flag, src, dst, deg);
    k_x2h<<<(N * 128 / 8 + 255) / 256, 256, 0, stream>>>(x, xh, N * 128);
    k_wfrag<<<16, 256, 0, stream>>>(Wl1, Wr1, w1f, 8);
    k_wfrag<<<16, 256, 0, stream>>>(Wl2, Wr2, w2f, 8);
    k_zfrag<<<16, 256, 0, stream>>>(Wm1, zwf);
    k_wefrag<<<2, 256, 0, stream>>>(Wm1, wef);

    k_bsum<<<nbk, 256, 0, stream>>>(deg, N, bsum);
    k_bscan<<<1, 256, 0, stream>>>(bsum, nbk, rowptr + N);
    k_rowptr<<<nbk, 256, 0, stream>>>(deg, N, bsum, rowptr, cursor);
    k_scatter<<<eb, 256, 0, stream>>>(src, dst, E, cursor, col, eid, dstp);

    // layer 1: agg(xh) + gemm -> h1
    k_fuse<0><<<rb64, 256, 0, stream>>>(xh, rowptr, col, w1f, b1, nullptr, nullptr, h1, N);
    // layer 2: agg(h1) + gemm + z-gemm -> z
    k_fuse<1><<<rb64, 256, 0, stream>>>(h1, rowptr, col, w2f, b2, zwf, bm1, z, N);

    const int eg = 1792;
    const int nb = (E + 63) / 64;
    const int e_iters = (nb + eg - 1) / eg;
    k_edge2<<<eg, 256, 0, stream>>>(z, ea, col, dstp, eid, wef, Wm2, bm2,
                                    tmp, E, e_iters, eg);
    k_perm<<<eb, 256, 0, stream>>>(tmp, eid, (float*)d_out, E);
}